// Round 2
// baseline (268.195 us; speedup 1.0000x reference)
//
#include <hip/hip_runtime.h>
#include <cstddef>

#define NROWS 8192

typedef __attribute__((ext_vector_type(8))) short bf16x8;
typedef __attribute__((ext_vector_type(4))) float f32x4;

__device__ __forceinline__ short f2bf(float f) {
  unsigned u = __float_as_uint(f);
  u += 0x7fffu + ((u >> 16) & 1u);   // RNE
  return (short)(u >> 16);
}
__device__ __forceinline__ float leaky_f(float v) { return v >= 0.0f ? v : 0.1f * v; }

// ---------------- Kernel 1: MLP encoder: x[8192,256] -> x2[8192,64], s, sq, x2bfT ----
extern "C" __global__ void __launch_bounds__(256)
encoder_kernel(const float* __restrict__ x, const float* __restrict__ W10,
               const float* __restrict__ b10, const float* __restrict__ W11,
               const float* __restrict__ b11, const float* __restrict__ avec,
               float* __restrict__ x2, float* __restrict__ sarr,
               float* __restrict__ sqarr, short* __restrict__ x2bfT) {
  __shared__ float xr[4][256];
  __shared__ float h1[4][128];
  const int t = threadIdx.x;
  const int r0 = blockIdx.x * 4;
#pragma unroll
  for (int r = 0; r < 4; ++r) xr[r][t] = x[(size_t)(r0 + r) * 256 + t];
  __syncthreads();
  if (t < 128) {
    float acc[4];
    const float b = b10[t];
#pragma unroll
    for (int r = 0; r < 4; ++r) acc[r] = b;
    const float* wrow = W10 + t * 256;
    for (int c = 0; c < 256; c += 4) {
      const float4 wv = *(const float4*)(wrow + c);
#pragma unroll
      for (int r = 0; r < 4; ++r) {
        acc[r] = fmaf(wv.x, xr[r][c], acc[r]);
        acc[r] = fmaf(wv.y, xr[r][c + 1], acc[r]);
        acc[r] = fmaf(wv.z, xr[r][c + 2], acc[r]);
        acc[r] = fmaf(wv.w, xr[r][c + 3], acc[r]);
      }
    }
#pragma unroll
    for (int r = 0; r < 4; ++r) h1[r][t] = leaky_f(acc[r]);
  }
  __syncthreads();
  if (t < 64) {
    float acc[4];
    const float b = b11[t];
#pragma unroll
    for (int r = 0; r < 4; ++r) acc[r] = b;
    const float* wrow = W11 + t * 128;
    for (int c = 0; c < 128; c += 4) {
      const float4 wv = *(const float4*)(wrow + c);
#pragma unroll
      for (int r = 0; r < 4; ++r) {
        acc[r] = fmaf(wv.x, h1[r][c], acc[r]);
        acc[r] = fmaf(wv.y, h1[r][c + 1], acc[r]);
        acc[r] = fmaf(wv.z, h1[r][c + 2], acc[r]);
        acc[r] = fmaf(wv.w, h1[r][c + 3], acc[r]);
      }
    }
    const float av = avec[t];
#pragma unroll
    for (int r = 0; r < 4; ++r) {
      const float v = leaky_f(acc[r]);
      x2[(size_t)(r0 + r) * 64 + t] = v;
      x2bfT[(size_t)t * NROWS + r0 + r] = f2bf(v);
      float ps = v * av, pq = v * v;
#pragma unroll
      for (int off = 1; off < 64; off <<= 1) {
        ps += __shfl_xor(ps, off);
        pq += __shfl_xor(pq, off);
      }
      if (t == 0) { sarr[r0 + r] = ps; sqarr[r0 + r] = pq * (1.0f / 64.0f); }
    }
  }
}

// ---------------- Kernel 2: barrier-free fused pass over A --------------------------
// Each wave owns 16 rows x full 64-d output. Raw values are computed directly in the
// MFMA A-fragment layout (lane l: row l&15, 8 consecutive j at (l>>4)*8), so there is
// no LDS round-trip and no per-tile barrier. A is double-buffered in registers.

__device__ __forceinline__ void do_tile(int tt, int ntiles,
    const float* __restrict__ Ap, const short* __restrict__ Bp,
    const float* __restrict__ sjb, const float* __restrict__ sqb,
    float si, float4 (&cur)[4], float4 (&nxt)[4],
    f32x4 (&acc)[4], float& prs, float& pss, float& pws) {
  const int off = tt * 64;
  // B fragments for this tile (L2-hot x2bfT)
  bf16x8 bfr[2][4];
#pragma unroll
  for (int ks = 0; ks < 2; ++ks)
#pragma unroll
    for (int n = 0; n < 4; ++n)
      bfr[ks][n] = *(const bf16x8*)(Bp + (size_t)n * 16 * NROWS + off + ks * 32);
  // prefetch next tile's A into the other register buffer
  const int pt = (tt + 1 == ntiles) ? 0 : tt + 1;
#pragma unroll
  for (int ks = 0; ks < 2; ++ks) {
    nxt[ks * 2]     = *(const float4*)(Ap + pt * 64 + ks * 32);
    nxt[ks * 2 + 1] = *(const float4*)(Ap + pt * 64 + ks * 32 + 4);
  }
  // compute raw = exp(leaky(si - sj)) * A, accumulate scalars, pack bf16
  bf16x8 araw[2];
#pragma unroll
  for (int ks = 0; ks < 2; ++ks) {
    const float4 sl = *(const float4*)(sjb + off + ks * 32);
    const float4 sh = *(const float4*)(sjb + off + ks * 32 + 4);
    const float4 ql = *(const float4*)(sqb + off + ks * 32);
    const float4 qh = *(const float4*)(sqb + off + ks * 32 + 4);
    const float4 al = cur[ks * 2];
    const float4 ah = cur[ks * 2 + 1];
    const float r0 = __expf(leaky_f(si - sl.x)) * al.x;
    const float r1 = __expf(leaky_f(si - sl.y)) * al.y;
    const float r2 = __expf(leaky_f(si - sl.z)) * al.z;
    const float r3 = __expf(leaky_f(si - sl.w)) * al.w;
    const float r4 = __expf(leaky_f(si - sh.x)) * ah.x;
    const float r5 = __expf(leaky_f(si - sh.y)) * ah.y;
    const float r6 = __expf(leaky_f(si - sh.z)) * ah.z;
    const float r7 = __expf(leaky_f(si - sh.w)) * ah.w;
    prs += ((r0 + r1) + (r2 + r3)) + ((r4 + r5) + (r6 + r7));
    pss = fmaf(r0, r0, pss); pss = fmaf(r1, r1, pss);
    pss = fmaf(r2, r2, pss); pss = fmaf(r3, r3, pss);
    pss = fmaf(r4, r4, pss); pss = fmaf(r5, r5, pss);
    pss = fmaf(r6, r6, pss); pss = fmaf(r7, r7, pss);
    pws = fmaf(r0, ql.x, pws); pws = fmaf(r1, ql.y, pws);
    pws = fmaf(r2, ql.z, pws); pws = fmaf(r3, ql.w, pws);
    pws = fmaf(r4, qh.x, pws); pws = fmaf(r5, qh.y, pws);
    pws = fmaf(r6, qh.z, pws); pws = fmaf(r7, qh.w, pws);
    bf16x8 p;
    p[0] = f2bf(r0); p[1] = f2bf(r1); p[2] = f2bf(r2); p[3] = f2bf(r3);
    p[4] = f2bf(r4); p[5] = f2bf(r5); p[6] = f2bf(r6); p[7] = f2bf(r7);
    araw[ks] = p;
  }
#pragma unroll
  for (int ks = 0; ks < 2; ++ks)
#pragma unroll
    for (int n = 0; n < 4; ++n)
      acc[n] = __builtin_amdgcn_mfma_f32_16x16x32_bf16(araw[ks], bfr[ks][n], acc[n], 0, 0, 0);
}

extern "C" __global__ void __launch_bounds__(256)
fused_attn_kernel(const float* __restrict__ A, const float* __restrict__ sarr,
                  const float* __restrict__ sqarr, const short* __restrict__ x2bfT,
                  float* __restrict__ yp, float* __restrict__ rsp,
                  float* __restrict__ ssp, float* __restrict__ wsp,
                  int jspan) {
  __shared__ float sjbuf[2048];
  __shared__ float sqbuf[2048];
  const int t = threadIdx.x;
  const int bi = blockIdx.x & 127;
  const int js = blockIdx.x >> 7;
  const int i0 = bi * 64;
  const int jbase = js * jspan;
  const int lane = t & 63;
  const int w = t >> 6;
  const int fr = lane & 15;
  const int kg = lane >> 4;
  const int ntiles = jspan >> 6;

  for (int k = t; k < jspan; k += 256) {
    sjbuf[k] = sarr[jbase + k];
    sqbuf[k] = sqarr[jbase + k];
  }
  const int irow = i0 + w * 16 + fr;
  const float si = sarr[irow];
  __syncthreads();   // the only barrier: sj/sqj staged once

  const float* Ap  = A + (size_t)irow * NROWS + jbase + kg * 8;
  const short* Bp  = x2bfT + (size_t)fr * NROWS + jbase + kg * 8;
  const float* sjb = sjbuf + kg * 8;
  const float* sqb = sqbuf + kg * 8;

  f32x4 acc[4];
#pragma unroll
  for (int n = 0; n < 4; ++n) acc[n] = (f32x4){0.f, 0.f, 0.f, 0.f};
  float prs = 0.f, pss = 0.f, pws = 0.f;

  float4 aA[4], aB[4];
#pragma unroll
  for (int ks = 0; ks < 2; ++ks) {
    aA[ks * 2]     = *(const float4*)(Ap + ks * 32);
    aA[ks * 2 + 1] = *(const float4*)(Ap + ks * 32 + 4);
  }

  for (int tt = 0; tt < ntiles; tt += 2) {
    do_tile(tt,     ntiles, Ap, Bp, sjb, sqb, si, aA, aB, acc, prs, pss, pws);
    do_tile(tt + 1, ntiles, Ap, Bp, sjb, sqb, si, aB, aA, acc, prs, pss, pws);
  }

  // combine the 4 k-groups holding the same row
#pragma unroll
  for (int off = 16; off < 64; off <<= 1) {
    prs += __shfl_xor(prs, off);
    pss += __shfl_xor(pss, off);
    pws += __shfl_xor(pws, off);
  }
  if (lane < 16) {
    const int gi = i0 + w * 16 + lane;
    rsp[js * NROWS + gi] = prs;
    ssp[js * NROWS + gi] = pss;
    wsp[js * NROWS + gi] = pws;
  }
  float* ypb = yp + (size_t)js * NROWS * 64;
#pragma unroll
  for (int n = 0; n < 4; ++n)
#pragma unroll
    for (int ri = 0; ri < 4; ++ri)
      ypb[(size_t)(i0 + w * 16 + kg * 4 + ri) * 64 + n * 16 + fr] = acc[n][ri];
}

// ---------------- Kernel 3: combine partials, GNN layer + head, per-row losses ------
extern "C" __global__ void __launch_bounds__(256)
finish_kernel(const float* __restrict__ x2, const float* __restrict__ sqarr,
              const float* __restrict__ yp, const float* __restrict__ rsp,
              const float* __restrict__ ssp, const float* __restrict__ wsp,
              const float* __restrict__ Wg, const float* __restrict__ bg,
              const float* __restrict__ W2, const float* __restrict__ b2,
              float* __restrict__ outp, float* __restrict__ l1c, float* __restrict__ l2c,
              int jsplit) {
  __shared__ float hbuf[4][64];
  __shared__ float gbuf[4][64];
  const int t = threadIdx.x;
  const int w = t >> 6, lane = t & 63;
  const int i = blockIdx.x * 4 + w;

  float yv = 0.f, rowsum = 0.f, sumsq = 0.f, wsq = 0.f;
  for (int p = 0; p < jsplit; ++p) {
    yv += yp[(size_t)p * NROWS * 64 + (size_t)i * 64 + lane];
    rowsum += rsp[p * NROWS + i];
    sumsq += ssp[p * NROWS + i];
    wsq += wsp[p * NROWS + i];
  }
  const float inv = 1.0f / rowsum;
  hbuf[w][lane] = yv * inv;
  const float xv = x2[(size_t)i * 64 + lane];
  float xy = xv * yv;
#pragma unroll
  for (int off = 1; off < 64; off <<= 1) xy += __shfl_xor(xy, off);
  if (lane == 0) {
    l1c[i] = sqarr[i] + (wsq - (2.0f / 64.0f) * xy) * inv;
    l2c[i] = sumsq * inv * inv;
  }
  __syncthreads();
  float accg = bg[lane];
  {
    const float* wrow = Wg + lane * 64;
#pragma unroll 4
    for (int d = 0; d < 64; ++d) accg = fmaf(wrow[d], hbuf[w][d], accg);
  }
  gbuf[w][lane] = leaky_f(accg);
  __syncthreads();
  if (lane < 32) {
    float acco = b2[lane];
    const float* wrow = W2 + lane * 64;
#pragma unroll 4
    for (int d = 0; d < 64; ++d) acco = fmaf(wrow[d], gbuf[w][d], acco);
    outp[(size_t)i * 32 + lane] = acco;
  }
}

// ---------------- Kernel 4: scalar loss reduction -----------------------------------
extern "C" __global__ void __launch_bounds__(256)
loss_kernel(const float* __restrict__ l1c, const float* __restrict__ l2c,
            float* __restrict__ outp) {
  __shared__ float s1[256], s2[256];
  const int t = threadIdx.x;
  float a1 = 0.f, a2 = 0.f;
  for (int i = t; i < NROWS; i += 256) { a1 += l1c[i]; a2 += l2c[i]; }
  s1[t] = a1; s2[t] = a2;
  __syncthreads();
  for (int off = 128; off > 0; off >>= 1) {
    if (t < off) { s1[t] += s1[t + off]; s2[t] += s2[t + off]; }
    __syncthreads();
  }
  if (t == 0) {
    const float scale = 1.0f / ((float)NROWS * (float)NROWS);
    outp[NROWS * 32] = s1[0] * scale;
    outp[NROWS * 32 + 1] = s2[0] * scale;
  }
}

// ---------------- launch ------------------------------------------------------------
extern "C" void kernel_launch(void* const* d_in, const int* in_sizes, int n_in,
                              void* d_out, int out_size, void* d_ws, size_t ws_size,
                              hipStream_t stream) {
  const float* x   = (const float*)d_in[0];
  const float* A   = (const float*)d_in[1];
  const float* W10 = (const float*)d_in[2];
  const float* b10 = (const float*)d_in[3];
  const float* W11 = (const float*)d_in[4];
  const float* b11 = (const float*)d_in[5];
  const float* av  = (const float*)d_in[6];
  const float* Wg  = (const float*)d_in[7];
  const float* bg  = (const float*)d_in[8];
  const float* W2  = (const float*)d_in[9];
  const float* b2  = (const float*)d_in[10];
  float* out = (float*)d_out;

  // choose j-split by available workspace
  const size_t fixed_floats = (size_t)NROWS * 64 + 4 * (size_t)NROWS;   // x2, sarr, sqarr, l1c, l2c
  auto need = [&](int js) {
    return (fixed_floats + (size_t)js * NROWS * 64 + 3 * (size_t)js * NROWS) * 4
           + (size_t)NROWS * 64 * 2;  // + x2bfT
  };
  int jsplit = (ws_size >= need(8)) ? 8 : 4;
  const int jspan = NROWS / jsplit;

  // workspace layout
  float* ws    = (float*)d_ws;
  float* x2    = ws;                                        // N*64
  float* sarr  = x2 + (size_t)NROWS * 64;                   // N
  float* sqarr = sarr + NROWS;                              // N
  float* yp    = sqarr + NROWS;                             // jsplit*N*64
  float* rsp   = yp + (size_t)jsplit * NROWS * 64;          // jsplit*N
  float* ssp   = rsp + (size_t)jsplit * NROWS;              // jsplit*N
  float* wsp   = ssp + (size_t)jsplit * NROWS;              // jsplit*N
  float* l1c   = wsp + (size_t)jsplit * NROWS;              // N
  float* l2c   = l1c + NROWS;                               // N
  short* x2bfT = (short*)(l2c + NROWS);                     // N*64 bf16 (transposed)

  hipLaunchKernelGGL(encoder_kernel, dim3(2048), dim3(256), 0, stream,
                     x, W10, b10, W11, b11, av, x2, sarr, sqarr, x2bfT);
  hipLaunchKernelGGL(fused_attn_kernel, dim3(128 * jsplit), dim3(256), 0, stream,
                     A, sarr, sqarr, x2bfT, yp, rsp, ssp, wsp, jspan);
  hipLaunchKernelGGL(finish_kernel, dim3(2048), dim3(256), 0, stream,
                     x2, sqarr, yp, rsp, ssp, wsp, Wg, bg, W2, b2, out, l1c, l2c, jsplit);
  hipLaunchKernelGGL(loss_kernel, dim3(1), dim3(256), 0, stream, l1c, l2c, out);
}

// Round 3
// 218.784 us; speedup vs baseline: 1.2258x; 1.2258x over previous
//
#include <hip/hip_runtime.h>
#include <hip/hip_bf16.h>
#include <cstddef>

#define NROWS 8192
#define LOG2E 1.4426950408889634f

typedef __attribute__((ext_vector_type(8))) short bf16x8;
typedef __attribute__((ext_vector_type(4))) float f32x4;

#if defined(__has_builtin) && __has_builtin(__builtin_amdgcn_exp2f)
#define EXP2(x) __builtin_amdgcn_exp2f(x)
#else
#define EXP2(x) __expf((x) * 0.6931471805599453f)
#endif

__device__ __forceinline__ short f2bf(float f) {
  unsigned u = __float_as_uint(f);
  u += 0x7fffu + ((u >> 16) & 1u);   // RNE
  return (short)(u >> 16);
}
__device__ __forceinline__ float leaky_f(float v) { return fmaxf(v, 0.1f * v); }

union BFPair { __hip_bfloat162 h; unsigned u; };
__device__ __forceinline__ unsigned pack2(float a, float b) {
  BFPair p;
  p.h = __float22bfloat162_rn(make_float2(a, b));  // -> v_cvt_pk_bf16_f32
  return p.u;
}

// ---------------- Kernel 1: MLP encoder: x[8192,256] -> x2[8192,64], s, sq, x2bfT ----
extern "C" __global__ void __launch_bounds__(256)
encoder_kernel(const float* __restrict__ x, const float* __restrict__ W10,
               const float* __restrict__ b10, const float* __restrict__ W11,
               const float* __restrict__ b11, const float* __restrict__ avec,
               float* __restrict__ x2, float* __restrict__ sarr,
               float* __restrict__ sqarr, short* __restrict__ x2bfT) {
  __shared__ float xr[4][256];
  __shared__ float h1[4][128];
  const int t = threadIdx.x;
  const int r0 = blockIdx.x * 4;
#pragma unroll
  for (int r = 0; r < 4; ++r) xr[r][t] = x[(size_t)(r0 + r) * 256 + t];
  __syncthreads();
  if (t < 128) {
    float acc[4];
    const float b = b10[t];
#pragma unroll
    for (int r = 0; r < 4; ++r) acc[r] = b;
    const float* wrow = W10 + t * 256;
    for (int c = 0; c < 256; c += 4) {
      const float4 wv = *(const float4*)(wrow + c);
#pragma unroll
      for (int r = 0; r < 4; ++r) {
        acc[r] = fmaf(wv.x, xr[r][c], acc[r]);
        acc[r] = fmaf(wv.y, xr[r][c + 1], acc[r]);
        acc[r] = fmaf(wv.z, xr[r][c + 2], acc[r]);
        acc[r] = fmaf(wv.w, xr[r][c + 3], acc[r]);
      }
    }
#pragma unroll
    for (int r = 0; r < 4; ++r) h1[r][t] = leaky_f(acc[r]);
  }
  __syncthreads();
  if (t < 64) {
    float acc[4];
    const float b = b11[t];
#pragma unroll
    for (int r = 0; r < 4; ++r) acc[r] = b;
    const float* wrow = W11 + t * 128;
    for (int c = 0; c < 128; c += 4) {
      const float4 wv = *(const float4*)(wrow + c);
#pragma unroll
      for (int r = 0; r < 4; ++r) {
        acc[r] = fmaf(wv.x, h1[r][c], acc[r]);
        acc[r] = fmaf(wv.y, h1[r][c + 1], acc[r]);
        acc[r] = fmaf(wv.z, h1[r][c + 2], acc[r]);
        acc[r] = fmaf(wv.w, h1[r][c + 3], acc[r]);
      }
    }
    const float av = avec[t];
#pragma unroll
    for (int r = 0; r < 4; ++r) {
      const float v = leaky_f(acc[r]);
      x2[(size_t)(r0 + r) * 64 + t] = v;
      x2bfT[(size_t)t * NROWS + r0 + r] = f2bf(v);
      float ps = v * av, pq = v * v;
#pragma unroll
      for (int off = 1; off < 64; off <<= 1) {
        ps += __shfl_xor(ps, off);
        pq += __shfl_xor(pq, off);
      }
      if (t == 0) {
        sarr[r0 + r] = ps * LOG2E;          // prescaled: exp(leaky(d)) = exp2(leaky(d*log2e))
        sqarr[r0 + r] = pq * (1.0f / 64.0f);
      }
    }
  }
}

// ---------------- Kernel 2: barrier-free fused pass over A --------------------------
// Each wave owns 16 rows x full 64-d output; raw values computed directly in the MFMA
// A-fragment layout (lane l: row l&15, 8 consecutive j at (l>>4)*8). A double-buffered
// in registers, HBM prefetch issued first each tile. __launch_bounds__(256,4): the grid
// is 4 blocks/CU, so cap VGPR at 128 and let the compiler keep the pipeline in regs.

__device__ __forceinline__ void do_tile(int tt, int ntiles,
    const float* __restrict__ Ap, const short* __restrict__ Bp,
    const float* __restrict__ sjb, const float* __restrict__ sqb,
    float si, float4 (&cur)[4], float4 (&nxt)[4],
    f32x4 (&acc)[4], float& prs, float& pss, float& pws) {
  const int off = tt * 64;
  const int pt = (tt + 1 == ntiles) ? 0 : tt + 1;
  // 1) HBM prefetch of next tile's A (longest latency: issue first)
#pragma unroll
  for (int ks = 0; ks < 2; ++ks) {
    nxt[ks * 2]     = *(const float4*)(Ap + pt * 64 + ks * 32);
    nxt[ks * 2 + 1] = *(const float4*)(Ap + pt * 64 + ks * 32 + 4);
  }
  // 2) B fragments for this tile (L2-hot x2bfT)
  bf16x8 bfr[2][4];
#pragma unroll
  for (int ks = 0; ks < 2; ++ks)
#pragma unroll
    for (int n = 0; n < 4; ++n)
      bfr[ks][n] = *(const bf16x8*)(Bp + (size_t)n * 16 * NROWS + off + ks * 32);
  // 3) raw = exp2(leaky(si - sj)) * A; accumulate rowsum/sumsq/wsq; pack bf16
  bf16x8 araw[2];
#pragma unroll
  for (int ks = 0; ks < 2; ++ks) {
    const float4 sl = *(const float4*)(sjb + off + ks * 32);
    const float4 sh = *(const float4*)(sjb + off + ks * 32 + 4);
    const float4 ql = *(const float4*)(sqb + off + ks * 32);
    const float4 qh = *(const float4*)(sqb + off + ks * 32 + 4);
    const float4 al = cur[ks * 2];
    const float4 ah = cur[ks * 2 + 1];
    const float r0 = EXP2(leaky_f(si - sl.x)) * al.x;
    const float r1 = EXP2(leaky_f(si - sl.y)) * al.y;
    const float r2 = EXP2(leaky_f(si - sl.z)) * al.z;
    const float r3 = EXP2(leaky_f(si - sl.w)) * al.w;
    const float r4 = EXP2(leaky_f(si - sh.x)) * ah.x;
    const float r5 = EXP2(leaky_f(si - sh.y)) * ah.y;
    const float r6 = EXP2(leaky_f(si - sh.z)) * ah.z;
    const float r7 = EXP2(leaky_f(si - sh.w)) * ah.w;
    prs += ((r0 + r1) + (r2 + r3)) + ((r4 + r5) + (r6 + r7));
    pss = fmaf(r0, r0, pss); pss = fmaf(r1, r1, pss);
    pss = fmaf(r2, r2, pss); pss = fmaf(r3, r3, pss);
    pss = fmaf(r4, r4, pss); pss = fmaf(r5, r5, pss);
    pss = fmaf(r6, r6, pss); pss = fmaf(r7, r7, pss);
    pws = fmaf(r0, ql.x, pws); pws = fmaf(r1, ql.y, pws);
    pws = fmaf(r2, ql.z, pws); pws = fmaf(r3, ql.w, pws);
    pws = fmaf(r4, qh.x, pws); pws = fmaf(r5, qh.y, pws);
    pws = fmaf(r6, qh.z, pws); pws = fmaf(r7, qh.w, pws);
    union { bf16x8 v; unsigned u[4]; } p;
    p.u[0] = pack2(r0, r1); p.u[1] = pack2(r2, r3);
    p.u[2] = pack2(r4, r5); p.u[3] = pack2(r6, r7);
    araw[ks] = p.v;
  }
  // 4) MFMA
#pragma unroll
  for (int ks = 0; ks < 2; ++ks)
#pragma unroll
    for (int n = 0; n < 4; ++n)
      acc[n] = __builtin_amdgcn_mfma_f32_16x16x32_bf16(araw[ks], bfr[ks][n], acc[n], 0, 0, 0);
}

extern "C" __global__ void __launch_bounds__(256, 4)
fused_attn_kernel(const float* __restrict__ A, const float* __restrict__ sarr,
                  const float* __restrict__ sqarr, const short* __restrict__ x2bfT,
                  float* __restrict__ yp, float* __restrict__ rsp,
                  float* __restrict__ ssp, float* __restrict__ wsp,
                  int jspan) {
  __shared__ float sjbuf[2048];
  __shared__ float sqbuf[2048];
  const int t = threadIdx.x;
  const int bi = blockIdx.x & 127;
  const int js = blockIdx.x >> 7;
  const int i0 = bi * 64;
  const int jbase = js * jspan;
  const int lane = t & 63;
  const int w = t >> 6;
  const int fr = lane & 15;
  const int kg = lane >> 4;
  const int ntiles = jspan >> 6;

  for (int k = t; k < jspan; k += 256) {
    sjbuf[k] = sarr[jbase + k];
    sqbuf[k] = sqarr[jbase + k];
  }
  const int irow = i0 + w * 16 + fr;
  const float si = sarr[irow];
  __syncthreads();   // the only barrier: sj/sqj staged once

  const float* Ap  = A + (size_t)irow * NROWS + jbase + kg * 8;
  const short* Bp  = x2bfT + (size_t)fr * NROWS + jbase + kg * 8;
  const float* sjb = sjbuf + kg * 8;
  const float* sqb = sqbuf + kg * 8;

  f32x4 acc[4];
#pragma unroll
  for (int n = 0; n < 4; ++n) acc[n] = (f32x4){0.f, 0.f, 0.f, 0.f};
  float prs = 0.f, pss = 0.f, pws = 0.f;

  float4 aA[4], aB[4];
#pragma unroll
  for (int ks = 0; ks < 2; ++ks) {
    aA[ks * 2]     = *(const float4*)(Ap + ks * 32);
    aA[ks * 2 + 1] = *(const float4*)(Ap + ks * 32 + 4);
  }

  for (int tt = 0; tt < ntiles; tt += 2) {
    do_tile(tt,     ntiles, Ap, Bp, sjb, sqb, si, aA, aB, acc, prs, pss, pws);
    do_tile(tt + 1, ntiles, Ap, Bp, sjb, sqb, si, aB, aA, acc, prs, pss, pws);
  }

  // combine the 4 k-groups holding the same row
#pragma unroll
  for (int off = 16; off < 64; off <<= 1) {
    prs += __shfl_xor(prs, off);
    pss += __shfl_xor(pss, off);
    pws += __shfl_xor(pws, off);
  }
  if (lane < 16) {
    const int gi = i0 + w * 16 + lane;
    rsp[js * NROWS + gi] = prs;
    ssp[js * NROWS + gi] = pss;
    wsp[js * NROWS + gi] = pws;
  }
  float* ypb = yp + (size_t)js * NROWS * 64;
#pragma unroll
  for (int n = 0; n < 4; ++n)
#pragma unroll
    for (int ri = 0; ri < 4; ++ri)
      ypb[(size_t)(i0 + w * 16 + kg * 4 + ri) * 64 + n * 16 + fr] = acc[n][ri];
}

// ---------------- Kernel 3: combine partials, GNN layer + head, per-row losses ------
extern "C" __global__ void __launch_bounds__(256)
finish_kernel(const float* __restrict__ x2, const float* __restrict__ sqarr,
              const float* __restrict__ yp, const float* __restrict__ rsp,
              const float* __restrict__ ssp, const float* __restrict__ wsp,
              const float* __restrict__ Wg, const float* __restrict__ bg,
              const float* __restrict__ W2, const float* __restrict__ b2,
              float* __restrict__ outp, float* __restrict__ l1c, float* __restrict__ l2c,
              int jsplit) {
  __shared__ float hbuf[4][64];
  __shared__ float gbuf[4][64];
  const int t = threadIdx.x;
  const int w = t >> 6, lane = t & 63;
  const int i = blockIdx.x * 4 + w;

  float yv = 0.f, rowsum = 0.f, sumsq = 0.f, wsq = 0.f;
#pragma unroll 4
  for (int p = 0; p < jsplit; ++p) {
    yv += yp[(size_t)p * NROWS * 64 + (size_t)i * 64 + lane];
    rowsum += rsp[p * NROWS + i];
    sumsq += ssp[p * NROWS + i];
    wsq += wsp[p * NROWS + i];
  }
  const float inv = 1.0f / rowsum;
  hbuf[w][lane] = yv * inv;
  const float xv = x2[(size_t)i * 64 + lane];
  float xy = xv * yv;
#pragma unroll
  for (int off = 1; off < 64; off <<= 1) xy += __shfl_xor(xy, off);
  if (lane == 0) {
    l1c[i] = sqarr[i] + (wsq - (2.0f / 64.0f) * xy) * inv;
    l2c[i] = sumsq * inv * inv;
  }
  __syncthreads();
  float accg = bg[lane];
  {
    const float* wrow = Wg + lane * 64;
#pragma unroll 4
    for (int d = 0; d < 64; ++d) accg = fmaf(wrow[d], hbuf[w][d], accg);
  }
  gbuf[w][lane] = leaky_f(accg);
  __syncthreads();
  if (lane < 32) {
    float acco = b2[lane];
    const float* wrow = W2 + lane * 64;
#pragma unroll 4
    for (int d = 0; d < 64; ++d) acco = fmaf(wrow[d], gbuf[w][d], acco);
    outp[(size_t)i * 32 + lane] = acco;
  }
}

// ---------------- Kernel 4: scalar loss reduction -----------------------------------
extern "C" __global__ void __launch_bounds__(256)
loss_kernel(const float* __restrict__ l1c, const float* __restrict__ l2c,
            float* __restrict__ outp) {
  __shared__ float s1[256], s2[256];
  const int t = threadIdx.x;
  float a1 = 0.f, a2 = 0.f;
  for (int i = t * 4; i < NROWS; i += 1024) {
    const float4 v1 = *(const float4*)(l1c + i);
    const float4 v2 = *(const float4*)(l2c + i);
    a1 += (v1.x + v1.y) + (v1.z + v1.w);
    a2 += (v2.x + v2.y) + (v2.z + v2.w);
  }
  s1[t] = a1; s2[t] = a2;
  __syncthreads();
  for (int off = 128; off > 0; off >>= 1) {
    if (t < off) { s1[t] += s1[t + off]; s2[t] += s2[t + off]; }
    __syncthreads();
  }
  if (t == 0) {
    const float scale = 1.0f / ((float)NROWS * (float)NROWS);
    outp[NROWS * 32] = s1[0] * scale;
    outp[NROWS * 32 + 1] = s2[0] * scale;
  }
}

// ---------------- launch ------------------------------------------------------------
extern "C" void kernel_launch(void* const* d_in, const int* in_sizes, int n_in,
                              void* d_out, int out_size, void* d_ws, size_t ws_size,
                              hipStream_t stream) {
  const float* x   = (const float*)d_in[0];
  const float* A   = (const float*)d_in[1];
  const float* W10 = (const float*)d_in[2];
  const float* b10 = (const float*)d_in[3];
  const float* W11 = (const float*)d_in[4];
  const float* b11 = (const float*)d_in[5];
  const float* av  = (const float*)d_in[6];
  const float* Wg  = (const float*)d_in[7];
  const float* bg  = (const float*)d_in[8];
  const float* W2  = (const float*)d_in[9];
  const float* b2  = (const float*)d_in[10];
  float* out = (float*)d_out;

  // choose j-split by available workspace
  const size_t fixed_floats = (size_t)NROWS * 64 + 4 * (size_t)NROWS;   // x2, sarr, sqarr, l1c, l2c
  auto need = [&](int js) {
    return (fixed_floats + (size_t)js * NROWS * 64 + 3 * (size_t)js * NROWS) * 4
           + (size_t)NROWS * 64 * 2;  // + x2bfT
  };
  int jsplit = (ws_size >= need(8)) ? 8 : 4;
  const int jspan = NROWS / jsplit;

  // workspace layout
  float* ws    = (float*)d_ws;
  float* x2    = ws;                                        // N*64
  float* sarr  = x2 + (size_t)NROWS * 64;                   // N
  float* sqarr = sarr + NROWS;                              // N
  float* yp    = sqarr + NROWS;                             // jsplit*N*64
  float* rsp   = yp + (size_t)jsplit * NROWS * 64;          // jsplit*N
  float* ssp   = rsp + (size_t)jsplit * NROWS;              // jsplit*N
  float* wsp   = ssp + (size_t)jsplit * NROWS;              // jsplit*N
  float* l1c   = wsp + (size_t)jsplit * NROWS;              // N
  float* l2c   = l1c + NROWS;                               // N
  short* x2bfT = (short*)(l2c + NROWS);                     // N*64 bf16 (transposed)

  hipLaunchKernelGGL(encoder_kernel, dim3(2048), dim3(256), 0, stream,
                     x, W10, b10, W11, b11, av, x2, sarr, sqarr, x2bfT);
  hipLaunchKernelGGL(fused_attn_kernel, dim3(128 * jsplit), dim3(256), 0, stream,
                     A, sarr, sqarr, x2bfT, yp, rsp, ssp, wsp, jspan);
  hipLaunchKernelGGL(finish_kernel, dim3(2048), dim3(256), 0, stream,
                     x2, sqarr, yp, rsp, ssp, wsp, Wg, bg, W2, b2, out, l1c, l2c, jsplit);
  hipLaunchKernelGGL(loss_kernel, dim3(1), dim3(256), 0, stream, l1c, l2c, out);
}

// Round 4
// 209.660 us; speedup vs baseline: 1.2792x; 1.0435x over previous
//
#include <hip/hip_runtime.h>
#include <hip/hip_bf16.h>
#include <cstddef>

#define NROWS 8192
#define LOG2E 1.4426950408889634f

typedef __attribute__((ext_vector_type(8))) short bf16x8;
typedef __attribute__((ext_vector_type(4))) float f32x4;

#if defined(__has_builtin) && __has_builtin(__builtin_amdgcn_exp2f)
#define EXP2(x) __builtin_amdgcn_exp2f(x)
#else
#define EXP2(x) __expf((x) * 0.6931471805599453f)
#endif

__device__ __forceinline__ short f2bf(float f) {
  unsigned u = __float_as_uint(f);
  u += 0x7fffu + ((u >> 16) & 1u);   // RNE
  return (short)(u >> 16);
}
__device__ __forceinline__ float leaky_f(float v) { return fmaxf(v, 0.1f * v); }

union BFPair { __hip_bfloat162 h; unsigned u; };
__device__ __forceinline__ unsigned pack2(float a, float b) {
  BFPair p;
  p.h = __float22bfloat162_rn(make_float2(a, b));  // -> v_cvt_pk_bf16_f32
  return p.u;
}

// ---------------- Kernel 1: MLP encoder: x[8192,256] -> x2[8192,64], s, sq, x2bfT ----
extern "C" __global__ void __launch_bounds__(256)
encoder_kernel(const float* __restrict__ x, const float* __restrict__ W10,
               const float* __restrict__ b10, const float* __restrict__ W11,
               const float* __restrict__ b11, const float* __restrict__ avec,
               float* __restrict__ x2, float* __restrict__ sarr,
               float* __restrict__ sqarr, short* __restrict__ x2bfT) {
  __shared__ float xr[4][256];
  __shared__ float h1[4][128];
  const int t = threadIdx.x;
  const int r0 = blockIdx.x * 4;
#pragma unroll
  for (int r = 0; r < 4; ++r) xr[r][t] = x[(size_t)(r0 + r) * 256 + t];
  __syncthreads();
  if (t < 128) {
    float acc[4];
    const float b = b10[t];
#pragma unroll
    for (int r = 0; r < 4; ++r) acc[r] = b;
    const float* wrow = W10 + t * 256;
    for (int c = 0; c < 256; c += 4) {
      const float4 wv = *(const float4*)(wrow + c);
#pragma unroll
      for (int r = 0; r < 4; ++r) {
        acc[r] = fmaf(wv.x, xr[r][c], acc[r]);
        acc[r] = fmaf(wv.y, xr[r][c + 1], acc[r]);
        acc[r] = fmaf(wv.z, xr[r][c + 2], acc[r]);
        acc[r] = fmaf(wv.w, xr[r][c + 3], acc[r]);
      }
    }
#pragma unroll
    for (int r = 0; r < 4; ++r) h1[r][t] = leaky_f(acc[r]);
  }
  __syncthreads();
  if (t < 64) {
    float acc[4];
    const float b = b11[t];
#pragma unroll
    for (int r = 0; r < 4; ++r) acc[r] = b;
    const float* wrow = W11 + t * 128;
    for (int c = 0; c < 128; c += 4) {
      const float4 wv = *(const float4*)(wrow + c);
#pragma unroll
      for (int r = 0; r < 4; ++r) {
        acc[r] = fmaf(wv.x, h1[r][c], acc[r]);
        acc[r] = fmaf(wv.y, h1[r][c + 1], acc[r]);
        acc[r] = fmaf(wv.z, h1[r][c + 2], acc[r]);
        acc[r] = fmaf(wv.w, h1[r][c + 3], acc[r]);
      }
    }
    const float av = avec[t];
#pragma unroll
    for (int r = 0; r < 4; ++r) {
      const float v = leaky_f(acc[r]);
      x2[(size_t)(r0 + r) * 64 + t] = v;
      x2bfT[(size_t)t * NROWS + r0 + r] = f2bf(v);
      float ps = v * av, pq = v * v;
#pragma unroll
      for (int off = 1; off < 64; off <<= 1) {
        ps += __shfl_xor(ps, off);
        pq += __shfl_xor(pq, off);
      }
      if (t == 0) {
        sarr[r0 + r] = ps * LOG2E;          // prescaled: exp(leaky(d)) = exp2(leaky(d*log2e))
        sqarr[r0 + r] = pq * (1.0f / 64.0f);
      }
    }
  }
}

// ---------------- Kernel 2: fused pass over A with manual counted-vmcnt pipeline ----
// Per tile (64 j): issue 8 B-loads, then 4 A-prefetch loads (next tile); vmcnt(12)
// retires only prev A before the exp phase; vmcnt(4) retires B before MFMA, keeping
// the A-prefetch in flight across the tile boundary (never drain to 0 in the loop).

#define LDG(dst, ptr, imm) \
  asm volatile("global_load_dwordx4 %0, %1, off offset:" imm \
               : "=v"(dst) : "v"(ptr) : "memory")
#define VMCNT(imm) \
  do { asm volatile("s_waitcnt vmcnt(" imm ")" ::: "memory"); \
       __builtin_amdgcn_sched_barrier(0); } while (0)

#define EXPPH(al, ah, sl, sh, ql, qh, dst) do {                         \
    const float r0 = EXP2(leaky_f(si - (sl)[0])) * (al)[0];             \
    const float r1 = EXP2(leaky_f(si - (sl)[1])) * (al)[1];             \
    const float r2 = EXP2(leaky_f(si - (sl)[2])) * (al)[2];             \
    const float r3 = EXP2(leaky_f(si - (sl)[3])) * (al)[3];             \
    const float r4 = EXP2(leaky_f(si - (sh)[0])) * (ah)[0];             \
    const float r5 = EXP2(leaky_f(si - (sh)[1])) * (ah)[1];             \
    const float r6 = EXP2(leaky_f(si - (sh)[2])) * (ah)[2];             \
    const float r7 = EXP2(leaky_f(si - (sh)[3])) * (ah)[3];             \
    prs += ((r0 + r1) + (r2 + r3)) + ((r4 + r5) + (r6 + r7));           \
    pss = fmaf(r0, r0, pss); pss = fmaf(r1, r1, pss);                   \
    pss = fmaf(r2, r2, pss); pss = fmaf(r3, r3, pss);                   \
    pss = fmaf(r4, r4, pss); pss = fmaf(r5, r5, pss);                   \
    pss = fmaf(r6, r6, pss); pss = fmaf(r7, r7, pss);                   \
    pws = fmaf(r0, (ql)[0], pws); pws = fmaf(r1, (ql)[1], pws);         \
    pws = fmaf(r2, (ql)[2], pws); pws = fmaf(r3, (ql)[3], pws);         \
    pws = fmaf(r4, (qh)[0], pws); pws = fmaf(r5, (qh)[1], pws);         \
    pws = fmaf(r6, (qh)[2], pws); pws = fmaf(r7, (qh)[3], pws);         \
    union { bf16x8 v; unsigned u[4]; } pk;                              \
    pk.u[0] = pack2(r0, r1); pk.u[1] = pack2(r2, r3);                   \
    pk.u[2] = pack2(r4, r5); pk.u[3] = pack2(r6, r7);                   \
    dst = pk.v;                                                         \
  } while (0)

#define ISSUE_B() do {                                  \
    LDG(b00, bPtr0, "0"); LDG(b10, bPtr0, "64");        \
    LDG(b01, bPtr1, "0"); LDG(b11, bPtr1, "64");        \
    LDG(b02, bPtr2, "0"); LDG(b12, bPtr2, "64");        \
    LDG(b03, bPtr3, "0"); LDG(b13, bPtr3, "64");        \
  } while (0)

#define LDS_SJ() \
    const f32x4 sl0 = *(const f32x4*)(sjbuf + so);          \
    const f32x4 sh0 = *(const f32x4*)(sjbuf + so + 4);      \
    const f32x4 ql0 = *(const f32x4*)(sqbuf + so);          \
    const f32x4 qh0 = *(const f32x4*)(sqbuf + so + 4);      \
    const f32x4 sl1 = *(const f32x4*)(sjbuf + so + 32);     \
    const f32x4 sh1 = *(const f32x4*)(sjbuf + so + 36);     \
    const f32x4 ql1 = *(const f32x4*)(sqbuf + so + 32);     \
    const f32x4 qh1 = *(const f32x4*)(sqbuf + so + 36)

#define DO_MFMA() do {                                                      \
    acc0 = __builtin_amdgcn_mfma_f32_16x16x32_bf16(araw0, b00, acc0, 0,0,0);\
    acc1 = __builtin_amdgcn_mfma_f32_16x16x32_bf16(araw0, b01, acc1, 0,0,0);\
    acc2 = __builtin_amdgcn_mfma_f32_16x16x32_bf16(araw0, b02, acc2, 0,0,0);\
    acc3 = __builtin_amdgcn_mfma_f32_16x16x32_bf16(araw0, b03, acc3, 0,0,0);\
    acc0 = __builtin_amdgcn_mfma_f32_16x16x32_bf16(araw1, b10, acc0, 0,0,0);\
    acc1 = __builtin_amdgcn_mfma_f32_16x16x32_bf16(araw1, b11, acc1, 0,0,0);\
    acc2 = __builtin_amdgcn_mfma_f32_16x16x32_bf16(araw1, b12, acc2, 0,0,0);\
    acc3 = __builtin_amdgcn_mfma_f32_16x16x32_bf16(araw1, b13, acc3, 0,0,0);\
  } while (0)

#define ADVANCE() do {                                  \
    aPtr += 64; bPtr0 += 64; bPtr1 += 64;               \
    bPtr2 += 64; bPtr3 += 64; so += 64;                 \
  } while (0)

// steady-state body: cur A regs (c0..c3) consumed, next tile prefetched into n0..n3
#define BODY(c0,c1,c2,c3, n0,n1,n2,n3) do {             \
    ISSUE_B();                                          \
    LDG(n0, aPtr, "256"); LDG(n1, aPtr, "272");         \
    LDG(n2, aPtr, "384"); LDG(n3, aPtr, "400");         \
    LDS_SJ();                                           \
    VMCNT("12");                                        \
    bf16x8 araw0, araw1;                                \
    EXPPH(c0, c1, sl0, sh0, ql0, qh0, araw0);           \
    EXPPH(c2, c3, sl1, sh1, ql1, qh1, araw1);           \
    VMCNT("4");                                         \
    DO_MFMA();                                          \
    ADVANCE();                                          \
  } while (0)

// tail body: no prefetch
#define TAIL(c0,c1,c2,c3) do {                          \
    ISSUE_B();                                          \
    LDS_SJ();                                           \
    VMCNT("8");                                         \
    bf16x8 araw0, araw1;                                \
    EXPPH(c0, c1, sl0, sh0, ql0, qh0, araw0);           \
    EXPPH(c2, c3, sl1, sh1, ql1, qh1, araw1);           \
    VMCNT("0");                                         \
    DO_MFMA();                                          \
  } while (0)

extern "C" __global__ void __launch_bounds__(256, 3)
fused_attn_kernel(const float* __restrict__ A, const float* __restrict__ sarr,
                  const float* __restrict__ sqarr, const short* __restrict__ x2bfT,
                  float* __restrict__ yp, float* __restrict__ rsp,
                  float* __restrict__ ssp, float* __restrict__ wsp,
                  int jspan) {
  __shared__ __attribute__((aligned(16))) float sjbuf[2048];
  __shared__ __attribute__((aligned(16))) float sqbuf[2048];
  const int t = threadIdx.x;
  const int bi = blockIdx.x & 127;
  const int js = blockIdx.x >> 7;
  const int i0 = bi * 64;
  const int jbase = js * jspan;
  const int lane = t & 63;
  const int w = t >> 6;
  const int fr = lane & 15;
  const int kg = lane >> 4;

  for (int k = t; k < jspan; k += 256) {
    sjbuf[k] = sarr[jbase + k];
    sqbuf[k] = sqarr[jbase + k];
  }
  const int irow = i0 + w * 16 + fr;
  const float si = sarr[irow];
  __syncthreads();   // also drains vmcnt: compiler-tracked loads all resolved here

  const float* aPtr = A + (size_t)irow * NROWS + jbase + kg * 8;
  const short* bPtr0 = x2bfT + (size_t)(0 * 16 + fr) * NROWS + jbase + kg * 8;
  const short* bPtr1 = x2bfT + (size_t)(1 * 16 + fr) * NROWS + jbase + kg * 8;
  const short* bPtr2 = x2bfT + (size_t)(2 * 16 + fr) * NROWS + jbase + kg * 8;
  const short* bPtr3 = x2bfT + (size_t)(3 * 16 + fr) * NROWS + jbase + kg * 8;
  int so = kg * 8;

  f32x4 acc0 = {0.f,0.f,0.f,0.f}, acc1 = {0.f,0.f,0.f,0.f};
  f32x4 acc2 = {0.f,0.f,0.f,0.f}, acc3 = {0.f,0.f,0.f,0.f};
  float prs = 0.f, pss = 0.f, pws = 0.f;

  f32x4 aX0, aX1, aX2, aX3, aY0, aY1, aY2, aY3;
  bf16x8 b00, b01, b02, b03, b10, b11, b12, b13;

  // prologue: tile 0 A-loads -> X   [4 outstanding = steady-state invariant]
  LDG(aX0, aPtr, "0"); LDG(aX1, aPtr, "16");
  LDG(aX2, aPtr, "128"); LDG(aX3, aPtr, "144");

  const int nloop = (jspan >> 7) - 1;   // ntiles/2 - 1
  for (int it = 0; it < nloop; ++it) {
    BODY(aX0, aX1, aX2, aX3, aY0, aY1, aY2, aY3);
    BODY(aY0, aY1, aY2, aY3, aX0, aX1, aX2, aX3);
  }
  BODY(aX0, aX1, aX2, aX3, aY0, aY1, aY2, aY3);   // tile ntiles-2
  TAIL(aY0, aY1, aY2, aY3);                       // tile ntiles-1

  // combine the 4 k-groups holding the same row
#pragma unroll
  for (int off = 16; off < 64; off <<= 1) {
    prs += __shfl_xor(prs, off);
    pss += __shfl_xor(pss, off);
    pws += __shfl_xor(pws, off);
  }
  if (lane < 16) {
    const int gi = i0 + w * 16 + lane;
    rsp[js * NROWS + gi] = prs;
    ssp[js * NROWS + gi] = pss;
    wsp[js * NROWS + gi] = pws;
  }
  float* ypb = yp + (size_t)js * NROWS * 64;
  f32x4 accs[4] = {acc0, acc1, acc2, acc3};
#pragma unroll
  for (int n = 0; n < 4; ++n)
#pragma unroll
    for (int ri = 0; ri < 4; ++ri)
      ypb[(size_t)(i0 + w * 16 + kg * 4 + ri) * 64 + n * 16 + fr] = accs[n][ri];
}

// ---------------- Kernel 3: combine partials, GNN layer + head, per-row losses ------
extern "C" __global__ void __launch_bounds__(256)
finish_kernel(const float* __restrict__ x2, const float* __restrict__ sqarr,
              const float* __restrict__ yp, const float* __restrict__ rsp,
              const float* __restrict__ ssp, const float* __restrict__ wsp,
              const float* __restrict__ Wg, const float* __restrict__ bg,
              const float* __restrict__ W2, const float* __restrict__ b2,
              float* __restrict__ outp, float* __restrict__ l1c, float* __restrict__ l2c,
              int jsplit) {
  __shared__ float hbuf[4][64];
  __shared__ float gbuf[4][64];
  const int t = threadIdx.x;
  const int w = t >> 6, lane = t & 63;
  const int i = blockIdx.x * 4 + w;

  float yv = 0.f, rowsum = 0.f, sumsq = 0.f, wsq = 0.f;
#pragma unroll 4
  for (int p = 0; p < jsplit; ++p) {
    yv += yp[(size_t)p * NROWS * 64 + (size_t)i * 64 + lane];
    rowsum += rsp[p * NROWS + i];
    sumsq += ssp[p * NROWS + i];
    wsq += wsp[p * NROWS + i];
  }
  const float inv = 1.0f / rowsum;
  hbuf[w][lane] = yv * inv;
  const float xv = x2[(size_t)i * 64 + lane];
  float xy = xv * yv;
#pragma unroll
  for (int off = 1; off < 64; off <<= 1) xy += __shfl_xor(xy, off);
  if (lane == 0) {
    l1c[i] = sqarr[i] + (wsq - (2.0f / 64.0f) * xy) * inv;
    l2c[i] = sumsq * inv * inv;
  }
  __syncthreads();
  float accg = bg[lane];
  {
    const float* wrow = Wg + lane * 64;
#pragma unroll 4
    for (int d = 0; d < 64; ++d) accg = fmaf(wrow[d], hbuf[w][d], accg);
  }
  gbuf[w][lane] = leaky_f(accg);
  __syncthreads();
  if (lane < 32) {
    float acco = b2[lane];
    const float* wrow = W2 + lane * 64;
#pragma unroll 4
    for (int d = 0; d < 64; ++d) acco = fmaf(wrow[d], gbuf[w][d], acco);
    outp[(size_t)i * 32 + lane] = acco;
  }
}

// ---------------- Kernel 4: scalar loss reduction -----------------------------------
extern "C" __global__ void __launch_bounds__(256)
loss_kernel(const float* __restrict__ l1c, const float* __restrict__ l2c,
            float* __restrict__ outp) {
  __shared__ float s1[256], s2[256];
  const int t = threadIdx.x;
  float a1 = 0.f, a2 = 0.f;
  for (int i = t * 4; i < NROWS; i += 1024) {
    const float4 v1 = *(const float4*)(l1c + i);
    const float4 v2 = *(const float4*)(l2c + i);
    a1 += (v1.x + v1.y) + (v1.z + v1.w);
    a2 += (v2.x + v2.y) + (v2.z + v2.w);
  }
  s1[t] = a1; s2[t] = a2;
  __syncthreads();
  for (int off = 128; off > 0; off >>= 1) {
    if (t < off) { s1[t] += s1[t + off]; s2[t] += s2[t + off]; }
    __syncthreads();
  }
  if (t == 0) {
    const float scale = 1.0f / ((float)NROWS * (float)NROWS);
    outp[NROWS * 32] = s1[0] * scale;
    outp[NROWS * 32 + 1] = s2[0] * scale;
  }
}

// ---------------- launch ------------------------------------------------------------
extern "C" void kernel_launch(void* const* d_in, const int* in_sizes, int n_in,
                              void* d_out, int out_size, void* d_ws, size_t ws_size,
                              hipStream_t stream) {
  const float* x   = (const float*)d_in[0];
  const float* A   = (const float*)d_in[1];
  const float* W10 = (const float*)d_in[2];
  const float* b10 = (const float*)d_in[3];
  const float* W11 = (const float*)d_in[4];
  const float* b11 = (const float*)d_in[5];
  const float* av  = (const float*)d_in[6];
  const float* Wg  = (const float*)d_in[7];
  const float* bg  = (const float*)d_in[8];
  const float* W2  = (const float*)d_in[9];
  const float* b2  = (const float*)d_in[10];
  float* out = (float*)d_out;

  // choose j-split by available workspace
  const size_t fixed_floats = (size_t)NROWS * 64 + 4 * (size_t)NROWS;   // x2, sarr, sqarr, l1c, l2c
  auto need = [&](int js) {
    return (fixed_floats + (size_t)js * NROWS * 64 + 3 * (size_t)js * NROWS) * 4
           + (size_t)NROWS * 64 * 2;  // + x2bfT
  };
  int jsplit = (ws_size >= need(8)) ? 8 : 4;
  const int jspan = NROWS / jsplit;

  // workspace layout
  float* ws    = (float*)d_ws;
  float* x2    = ws;                                        // N*64
  float* sarr  = x2 + (size_t)NROWS * 64;                   // N
  float* sqarr = sarr + NROWS;                              // N
  float* yp    = sqarr + NROWS;                             // jsplit*N*64
  float* rsp   = yp + (size_t)jsplit * NROWS * 64;          // jsplit*N
  float* ssp   = rsp + (size_t)jsplit * NROWS;              // jsplit*N
  float* wsp   = ssp + (size_t)jsplit * NROWS;              // jsplit*N
  float* l1c   = wsp + (size_t)jsplit * NROWS;              // N
  float* l2c   = l1c + NROWS;                               // N
  short* x2bfT = (short*)(l2c + NROWS);                     // N*64 bf16 (transposed)

  hipLaunchKernelGGL(encoder_kernel, dim3(2048), dim3(256), 0, stream,
                     x, W10, b10, W11, b11, av, x2, sarr, sqarr, x2bfT);
  hipLaunchKernelGGL(fused_attn_kernel, dim3(128 * jsplit), dim3(256), 0, stream,
                     A, sarr, sqarr, x2bfT, yp, rsp, ssp, wsp, jspan);
  hipLaunchKernelGGL(finish_kernel, dim3(2048), dim3(256), 0, stream,
                     x2, sqarr, yp, rsp, ssp, wsp, Wg, bg, W2, b2, out, l1c, l2c, jsplit);
  hipLaunchKernelGGL(loss_kernel, dim3(1), dim3(256), 0, stream, l1c, l2c, out);
}

// Round 5
// 202.452 us; speedup vs baseline: 1.3247x; 1.0356x over previous
//
#include <hip/hip_runtime.h>
#include <hip/hip_bf16.h>
#include <cstddef>

#define NROWS 8192
#define LOG2E 1.4426950408889634f

typedef __attribute__((ext_vector_type(8))) short bf16x8;
typedef __attribute__((ext_vector_type(4))) float f32x4;

#if defined(__has_builtin) && __has_builtin(__builtin_amdgcn_exp2f)
#define EXP2(x) __builtin_amdgcn_exp2f(x)
#else
#define EXP2(x) __expf((x) * 0.6931471805599453f)
#endif

__device__ __forceinline__ short f2bf(float f) {
  unsigned u = __float_as_uint(f);
  u += 0x7fffu + ((u >> 16) & 1u);   // RNE
  return (short)(u >> 16);
}
__device__ __forceinline__ float leaky_f(float v) { return fmaxf(v, 0.1f * v); }

union BFPair { __hip_bfloat162 h; unsigned u; };
__device__ __forceinline__ unsigned pack2(float a, float b) {
  BFPair p;
  p.h = __float22bfloat162_rn(make_float2(a, b));  // -> v_cvt_pk_bf16_f32
  return p.u;
}

// ---------------- Kernel 1: MLP encoder: x[8192,256] -> x2[8192,64], s, sq, x2bfT ----
extern "C" __global__ void __launch_bounds__(256)
encoder_kernel(const float* __restrict__ x, const float* __restrict__ W10,
               const float* __restrict__ b10, const float* __restrict__ W11,
               const float* __restrict__ b11, const float* __restrict__ avec,
               float* __restrict__ x2, float* __restrict__ sarr,
               float* __restrict__ sqarr, short* __restrict__ x2bfT) {
  __shared__ float xr[4][256];
  __shared__ float h1[4][128];
  const int t = threadIdx.x;
  const int r0 = blockIdx.x * 4;
#pragma unroll
  for (int r = 0; r < 4; ++r) xr[r][t] = x[(size_t)(r0 + r) * 256 + t];
  __syncthreads();
  if (t < 128) {
    float acc[4];
    const float b = b10[t];
#pragma unroll
    for (int r = 0; r < 4; ++r) acc[r] = b;
    const float* wrow = W10 + t * 256;
    for (int c = 0; c < 256; c += 4) {
      const float4 wv = *(const float4*)(wrow + c);
#pragma unroll
      for (int r = 0; r < 4; ++r) {
        acc[r] = fmaf(wv.x, xr[r][c], acc[r]);
        acc[r] = fmaf(wv.y, xr[r][c + 1], acc[r]);
        acc[r] = fmaf(wv.z, xr[r][c + 2], acc[r]);
        acc[r] = fmaf(wv.w, xr[r][c + 3], acc[r]);
      }
    }
#pragma unroll
    for (int r = 0; r < 4; ++r) h1[r][t] = leaky_f(acc[r]);
  }
  __syncthreads();
  if (t < 64) {
    float acc[4];
    const float b = b11[t];
#pragma unroll
    for (int r = 0; r < 4; ++r) acc[r] = b;
    const float* wrow = W11 + t * 128;
    for (int c = 0; c < 128; c += 4) {
      const float4 wv = *(const float4*)(wrow + c);
#pragma unroll
      for (int r = 0; r < 4; ++r) {
        acc[r] = fmaf(wv.x, h1[r][c], acc[r]);
        acc[r] = fmaf(wv.y, h1[r][c + 1], acc[r]);
        acc[r] = fmaf(wv.z, h1[r][c + 2], acc[r]);
        acc[r] = fmaf(wv.w, h1[r][c + 3], acc[r]);
      }
    }
    const float av = avec[t];
#pragma unroll
    for (int r = 0; r < 4; ++r) {
      const float v = leaky_f(acc[r]);
      x2[(size_t)(r0 + r) * 64 + t] = v;
      x2bfT[(size_t)t * NROWS + r0 + r] = f2bf(v);
      float ps = v * av, pq = v * v;
#pragma unroll
      for (int off = 1; off < 64; off <<= 1) {
        ps += __shfl_xor(ps, off);
        pq += __shfl_xor(pq, off);
      }
      if (t == 0) {
        sarr[r0 + r] = ps * LOG2E;          // prescaled: exp(leaky(d)) = exp2(leaky(d*log2e))
        sqarr[r0 + r] = pq * (1.0f / 64.0f);
      }
    }
  }
}

// ---------------- Kernel 2: fused pass over A, counted-vmcnt + tile-phase stagger ---
// Per tile: 8 B-loads (this tile), 4 A-loads (next tile, modular); vmcnt(12) retires
// only the current tile's A before the exp phase; vmcnt(4) retires B before MFMA,
// keeping the A-prefetch in flight across the tile boundary. Each block starts at a
// rotated tile phase so blocks spread uniformly over HBM channels / L3 slices.

#define LDG(dst, ptr, imm) \
  asm volatile("global_load_dwordx4 %0, %1, off offset:" imm \
               : "=v"(dst) : "v"(ptr) : "memory")
#define VMCNT(imm) \
  do { asm volatile("s_waitcnt vmcnt(" imm ")" ::: "memory"); \
       __builtin_amdgcn_sched_barrier(0); } while (0)

#define EXPPH(al, ah, sl, sh, ql, qh, dst) do {                         \
    const float r0 = EXP2(leaky_f(si - (sl)[0])) * (al)[0];             \
    const float r1 = EXP2(leaky_f(si - (sl)[1])) * (al)[1];             \
    const float r2 = EXP2(leaky_f(si - (sl)[2])) * (al)[2];             \
    const float r3 = EXP2(leaky_f(si - (sl)[3])) * (al)[3];             \
    const float r4 = EXP2(leaky_f(si - (sh)[0])) * (ah)[0];             \
    const float r5 = EXP2(leaky_f(si - (sh)[1])) * (ah)[1];             \
    const float r6 = EXP2(leaky_f(si - (sh)[2])) * (ah)[2];             \
    const float r7 = EXP2(leaky_f(si - (sh)[3])) * (ah)[3];             \
    prs += ((r0 + r1) + (r2 + r3)) + ((r4 + r5) + (r6 + r7));           \
    pss = fmaf(r0, r0, pss); pss = fmaf(r1, r1, pss);                   \
    pss = fmaf(r2, r2, pss); pss = fmaf(r3, r3, pss);                   \
    pss = fmaf(r4, r4, pss); pss = fmaf(r5, r5, pss);                   \
    pss = fmaf(r6, r6, pss); pss = fmaf(r7, r7, pss);                   \
    pws = fmaf(r0, (ql)[0], pws); pws = fmaf(r1, (ql)[1], pws);         \
    pws = fmaf(r2, (ql)[2], pws); pws = fmaf(r3, (ql)[3], pws);         \
    pws = fmaf(r4, (qh)[0], pws); pws = fmaf(r5, (qh)[1], pws);         \
    pws = fmaf(r6, (qh)[2], pws); pws = fmaf(r7, (qh)[3], pws);         \
    union { bf16x8 v; unsigned u[4]; } pk;                              \
    pk.u[0] = pack2(r0, r1); pk.u[1] = pack2(r2, r3);                   \
    pk.u[2] = pack2(r4, r5); pk.u[3] = pack2(r6, r7);                   \
    dst = pk.v;                                                         \
  } while (0)

#define DO_MFMA() do {                                                      \
    acc0 = __builtin_amdgcn_mfma_f32_16x16x32_bf16(araw0, b00, acc0, 0,0,0);\
    acc1 = __builtin_amdgcn_mfma_f32_16x16x32_bf16(araw0, b01, acc1, 0,0,0);\
    acc2 = __builtin_amdgcn_mfma_f32_16x16x32_bf16(araw0, b02, acc2, 0,0,0);\
    acc3 = __builtin_amdgcn_mfma_f32_16x16x32_bf16(araw0, b03, acc3, 0,0,0);\
    acc0 = __builtin_amdgcn_mfma_f32_16x16x32_bf16(araw1, b10, acc0, 0,0,0);\
    acc1 = __builtin_amdgcn_mfma_f32_16x16x32_bf16(araw1, b11, acc1, 0,0,0);\
    acc2 = __builtin_amdgcn_mfma_f32_16x16x32_bf16(araw1, b12, acc2, 0,0,0);\
    acc3 = __builtin_amdgcn_mfma_f32_16x16x32_bf16(araw1, b13, acc3, 0,0,0);\
  } while (0)

// one tile, modular phase: consume A regs c0..c3, prefetch next tile into n0..n3
#define BODY(tt, c0,c1,c2,c3, n0,n1,n2,n3) do {                 \
    const int toff  = (((tt) + rot) & (NT - 1)) * 64;           \
    const int toffn = (((tt) + 1 + rot) & (NT - 1)) * 64;       \
    const short* bP0 = bB0 + toff;                              \
    const short* bP1 = bB1 + toff;                              \
    const short* bP2 = bB2 + toff;                              \
    const short* bP3 = bB3 + toff;                              \
    const float* aPn = aB + toffn;                              \
    LDG(b00, bP0, "0"); LDG(b10, bP0, "64");                    \
    LDG(b01, bP1, "0"); LDG(b11, bP1, "64");                    \
    LDG(b02, bP2, "0"); LDG(b12, bP2, "64");                    \
    LDG(b03, bP3, "0"); LDG(b13, bP3, "64");                    \
    LDG(n0, aPn, "0");  LDG(n1, aPn, "16");                     \
    LDG(n2, aPn, "128"); LDG(n3, aPn, "144");                   \
    const int so = kg * 8 + toff;                               \
    const f32x4 sl0 = *(const f32x4*)(sjbuf + so);              \
    const f32x4 sh0 = *(const f32x4*)(sjbuf + so + 4);          \
    const f32x4 ql0 = *(const f32x4*)(sqbuf + so);              \
    const f32x4 qh0 = *(const f32x4*)(sqbuf + so + 4);          \
    const f32x4 sl1 = *(const f32x4*)(sjbuf + so + 32);         \
    const f32x4 sh1 = *(const f32x4*)(sjbuf + so + 36);         \
    const f32x4 ql1 = *(const f32x4*)(sqbuf + so + 32);         \
    const f32x4 qh1 = *(const f32x4*)(sqbuf + so + 36);         \
    VMCNT("12");                                                \
    bf16x8 araw0, araw1;                                        \
    EXPPH(c0, c1, sl0, sh0, ql0, qh0, araw0);                   \
    EXPPH(c2, c3, sl1, sh1, ql1, qh1, araw1);                   \
    VMCNT("4");                                                 \
    DO_MFMA();                                                  \
  } while (0)

template <int NT>   // tiles per j-window (jspan = NT*64); power of two
__global__ void __launch_bounds__(256, 3)
fused_attn_kernel(const float* __restrict__ A, const float* __restrict__ sarr,
                  const float* __restrict__ sqarr, const short* __restrict__ x2bfT,
                  float* __restrict__ yp, float* __restrict__ rsp,
                  float* __restrict__ ssp, float* __restrict__ wsp) {
  constexpr int JSPAN = NT * 64;
  __shared__ __attribute__((aligned(16))) float sjbuf[JSPAN];
  __shared__ __attribute__((aligned(16))) float sqbuf[JSPAN];
  const int t = threadIdx.x;
  const int bi = blockIdx.x & 127;
  const int js = blockIdx.x >> 7;
  const int i0 = bi * 64;
  const int jbase = js * JSPAN;
  const int lane = t & 63;
  const int w = t >> 6;
  const int fr = lane & 15;
  const int kg = lane >> 4;
  const int rot = (bi + js * 5) & (NT - 1);   // per-block column-phase stagger

  for (int k = t; k < JSPAN; k += 256) {
    sjbuf[k] = sarr[jbase + k];
    sqbuf[k] = sqarr[jbase + k];
  }
  const int irow = i0 + w * 16 + fr;
  const float si = sarr[irow];
  __syncthreads();   // also drains vmcnt: compiler-tracked loads all resolved here

  const float* aB  = A + (size_t)irow * NROWS + jbase + kg * 8;
  const short* bB0 = x2bfT + (size_t)(0 * 16 + fr) * NROWS + jbase + kg * 8;
  const short* bB1 = x2bfT + (size_t)(1 * 16 + fr) * NROWS + jbase + kg * 8;
  const short* bB2 = x2bfT + (size_t)(2 * 16 + fr) * NROWS + jbase + kg * 8;
  const short* bB3 = x2bfT + (size_t)(3 * 16 + fr) * NROWS + jbase + kg * 8;

  f32x4 acc0 = {0.f,0.f,0.f,0.f}, acc1 = {0.f,0.f,0.f,0.f};
  f32x4 acc2 = {0.f,0.f,0.f,0.f}, acc3 = {0.f,0.f,0.f,0.f};
  float prs = 0.f, pss = 0.f, pws = 0.f;

  f32x4 aX0, aX1, aX2, aX3, aY0, aY1, aY2, aY3;
  bf16x8 b00, b01, b02, b03, b10, b11, b12, b13;

  // prologue: A-loads for tile 'rot'  [4 outstanding = steady-state invariant]
  {
    const float* aP0 = aB + rot * 64;
    LDG(aX0, aP0, "0"); LDG(aX1, aP0, "16");
    LDG(aX2, aP0, "128"); LDG(aX3, aP0, "144");
  }

#pragma unroll 1
  for (int tt = 0; tt < NT; tt += 2) {
    BODY(tt,     aX0, aX1, aX2, aX3, aY0, aY1, aY2, aY3);
    BODY(tt + 1, aY0, aY1, aY2, aY3, aX0, aX1, aX2, aX3);
  }
  VMCNT("0");   // drain the final (wrapped, unused) prefetch

  // combine the 4 k-groups holding the same row
#pragma unroll
  for (int off = 16; off < 64; off <<= 1) {
    prs += __shfl_xor(prs, off);
    pss += __shfl_xor(pss, off);
    pws += __shfl_xor(pws, off);
  }
  if (lane < 16) {
    const int gi = i0 + w * 16 + lane;
    rsp[js * NROWS + gi] = prs;
    ssp[js * NROWS + gi] = pss;
    wsp[js * NROWS + gi] = pws;
  }
  float* ypb = yp + (size_t)js * NROWS * 64;
  f32x4 accs[4] = {acc0, acc1, acc2, acc3};
#pragma unroll
  for (int n = 0; n < 4; ++n)
#pragma unroll
    for (int ri = 0; ri < 4; ++ri)
      ypb[(size_t)(i0 + w * 16 + kg * 4 + ri) * 64 + n * 16 + fr] = accs[n][ri];
}

// ---------------- Kernel 3: combine partials, GNN layer + head, per-row losses ------
extern "C" __global__ void __launch_bounds__(256)
finish_kernel(const float* __restrict__ x2, const float* __restrict__ sqarr,
              const float* __restrict__ yp, const float* __restrict__ rsp,
              const float* __restrict__ ssp, const float* __restrict__ wsp,
              const float* __restrict__ Wg, const float* __restrict__ bg,
              const float* __restrict__ W2, const float* __restrict__ b2,
              float* __restrict__ outp, float* __restrict__ l1c, float* __restrict__ l2c,
              int jsplit) {
  __shared__ float hbuf[4][64];
  __shared__ float gbuf[4][64];
  const int t = threadIdx.x;
  const int w = t >> 6, lane = t & 63;
  const int i = blockIdx.x * 4 + w;

  float yv = 0.f, rowsum = 0.f, sumsq = 0.f, wsq = 0.f;
#pragma unroll 4
  for (int p = 0; p < jsplit; ++p) {
    yv += yp[(size_t)p * NROWS * 64 + (size_t)i * 64 + lane];
    rowsum += rsp[p * NROWS + i];
    sumsq += ssp[p * NROWS + i];
    wsq += wsp[p * NROWS + i];
  }
  const float inv = 1.0f / rowsum;
  hbuf[w][lane] = yv * inv;
  const float xv = x2[(size_t)i * 64 + lane];
  float xy = xv * yv;
#pragma unroll
  for (int off = 1; off < 64; off <<= 1) xy += __shfl_xor(xy, off);
  if (lane == 0) {
    l1c[i] = sqarr[i] + (wsq - (2.0f / 64.0f) * xy) * inv;
    l2c[i] = sumsq * inv * inv;
  }
  __syncthreads();
  float accg = bg[lane];
  {
    const float* wrow = Wg + lane * 64;
#pragma unroll 4
    for (int d = 0; d < 64; ++d) accg = fmaf(wrow[d], hbuf[w][d], accg);
  }
  gbuf[w][lane] = leaky_f(accg);
  __syncthreads();
  if (lane < 32) {
    float acco = b2[lane];
    const float* wrow = W2 + lane * 64;
#pragma unroll 4
    for (int d = 0; d < 64; ++d) acco = fmaf(wrow[d], gbuf[w][d], acco);
    outp[(size_t)i * 32 + lane] = acco;
  }
}

// ---------------- Kernel 4: scalar loss reduction -----------------------------------
extern "C" __global__ void __launch_bounds__(256)
loss_kernel(const float* __restrict__ l1c, const float* __restrict__ l2c,
            float* __restrict__ outp) {
  __shared__ float s1[256], s2[256];
  const int t = threadIdx.x;
  float a1 = 0.f, a2 = 0.f;
  for (int i = t * 4; i < NROWS; i += 1024) {
    const float4 v1 = *(const float4*)(l1c + i);
    const float4 v2 = *(const float4*)(l2c + i);
    a1 += (v1.x + v1.y) + (v1.z + v1.w);
    a2 += (v2.x + v2.y) + (v2.z + v2.w);
  }
  s1[t] = a1; s2[t] = a2;
  __syncthreads();
  for (int off = 128; off > 0; off >>= 1) {
    if (t < off) { s1[t] += s1[t + off]; s2[t] += s2[t + off]; }
    __syncthreads();
  }
  if (t == 0) {
    const float scale = 1.0f / ((float)NROWS * (float)NROWS);
    outp[NROWS * 32] = s1[0] * scale;
    outp[NROWS * 32 + 1] = s2[0] * scale;
  }
}

// ---------------- launch ------------------------------------------------------------
extern "C" void kernel_launch(void* const* d_in, const int* in_sizes, int n_in,
                              void* d_out, int out_size, void* d_ws, size_t ws_size,
                              hipStream_t stream) {
  const float* x   = (const float*)d_in[0];
  const float* A   = (const float*)d_in[1];
  const float* W10 = (const float*)d_in[2];
  const float* b10 = (const float*)d_in[3];
  const float* W11 = (const float*)d_in[4];
  const float* b11 = (const float*)d_in[5];
  const float* av  = (const float*)d_in[6];
  const float* Wg  = (const float*)d_in[7];
  const float* bg  = (const float*)d_in[8];
  const float* W2  = (const float*)d_in[9];
  const float* b2  = (const float*)d_in[10];
  float* out = (float*)d_out;

  // choose j-split by available workspace
  const size_t fixed_floats = (size_t)NROWS * 64 + 4 * (size_t)NROWS;   // x2, sarr, sqarr, l1c, l2c
  auto need = [&](int js) {
    return (fixed_floats + (size_t)js * NROWS * 64 + 3 * (size_t)js * NROWS) * 4
           + (size_t)NROWS * 64 * 2;  // + x2bfT
  };
  int jsplit = (ws_size >= need(8)) ? 8 : 4;

  // workspace layout
  float* ws    = (float*)d_ws;
  float* x2    = ws;                                        // N*64
  float* sarr  = x2 + (size_t)NROWS * 64;                   // N
  float* sqarr = sarr + NROWS;                              // N
  float* yp    = sqarr + NROWS;                             // jsplit*N*64
  float* rsp   = yp + (size_t)jsplit * NROWS * 64;          // jsplit*N
  float* ssp   = rsp + (size_t)jsplit * NROWS;              // jsplit*N
  float* wsp   = ssp + (size_t)jsplit * NROWS;              // jsplit*N
  float* l1c   = wsp + (size_t)jsplit * NROWS;              // N
  float* l2c   = l1c + NROWS;                               // N
  short* x2bfT = (short*)(l2c + NROWS);                     // N*64 bf16 (transposed)

  hipLaunchKernelGGL(encoder_kernel, dim3(2048), dim3(256), 0, stream,
                     x, W10, b10, W11, b11, av, x2, sarr, sqarr, x2bfT);
  if (jsplit == 8) {
    hipLaunchKernelGGL((fused_attn_kernel<16>), dim3(128 * 8), dim3(256), 0, stream,
                       A, sarr, sqarr, x2bfT, yp, rsp, ssp, wsp);
  } else {
    hipLaunchKernelGGL((fused_attn_kernel<32>), dim3(128 * 4), dim3(256), 0, stream,
                       A, sarr, sqarr, x2bfT, yp, rsp, ssp, wsp);
  }
  hipLaunchKernelGGL(finish_kernel, dim3(2048), dim3(256), 0, stream,
                     x2, sqarr, yp, rsp, ssp, wsp, Wg, bg, W2, b2, out, l1c, l2c, jsplit);
  hipLaunchKernelGGL(loss_kernel, dim3(1), dim3(256), 0, stream, l1c, l2c, out);
}